// Round 6
// baseline (165.875 us; speedup 1.0000x reference)
//
#include <hip/hip_runtime.h>

// GCN 2-layer. R18: fix R17's intra-dispatch race. R17 fused the WT1/WT2
// transpose blocks and the gemm1 blocks (which READ WT1) into one dispatch;
// block order is undefined -> gemm1 strips consumed half-written weights
// (absmax 0.175). Fix: tiny k_pre kernel (WT transpose + cnt zeroing, 176
// blocks) launched first; k_front keeps scatter || gemm1raw only. Every
// producer->consumer edge now crosses a kernel boundary. Still 4 enqueues
// (k_pre replaces the hipMemsetAsync).
// R17 design retained: deferred-dinv algebra (G = x@W1 raw ->
//   h1_d = relu(dvd*(sum dvs*G_s + dvd*G_d) + b1), g2 = h1@W2 raw,
//   out_d = dvd*(sum dvs*g2_s + dvd*g2_d) + b2), per-edge dvs from cnt
// (80KB, L2-hot); k_mid fuses agg128+gemm2 per 16-node strip with the h1
// tile in LDS only (h1p global round-trip eliminated, ~10MB).
// Pipeline: k_pre -> k_front(scatter || gemm1raw) -> k_mid -> k_back.

#define N_NODES 20000
#define N_EDGES 640000
#define IN_DIM 128
#define HID_DIM 128
#define OUT_DIM 64

#define STRIDE 80
#define SCAT_NB (N_EDGES / 256)              // 2500
#define G1_NB 625                            // 2500 wave-tasks / 4
#define G1_TASKS (2 * (N_NODES / 16))        // 2500
#define PRE_ITEMS (128 * 128 + 64 * 128 + N_NODES)
#define PRE_NB ((PRE_ITEMS + 255) / 256)     // 176

typedef _Float16 half8_t __attribute__((ext_vector_type(8)));
typedef float float4_t __attribute__((ext_vector_type(4)));

// k_pre: WT1/WT2 transpose+cast (fp32 [k][c] -> fp16 [c][k]) + cnt zeroing.
__global__ __launch_bounds__(256) void k_pre(const float* __restrict__ W1,
                                             const float* __restrict__ W2,
                                             _Float16* __restrict__ WT1,
                                             _Float16* __restrict__ WT2,
                                             int* __restrict__ cnt) {
    int i = blockIdx.x * 256 + threadIdx.x;
    if (i < 128 * 128) {
        int c = i >> 7, k = i & 127;
        WT1[i] = (_Float16)W1[k * 128 + c];
    } else if (i < 128 * 128 + 64 * 128) {
        int o = i - 128 * 128;
        int c = o >> 7, k = o & 127;
        WT2[o] = (_Float16)W2[k * 64 + c];
    } else {
        int n = i - (128 * 128 + 64 * 128);
        if (n < N_NODES) cnt[n] = 0;
    }
}

// k_front: blocks [0,SCAT_NB): atomic scatter (1 edge/thread) -> u16 padded
// buckets + cnt. blocks [SCAT_NB,...): gemm1 RAW G = x@W1 (deferred dinv ->
// no dependence on the scatter; WT1 comes from k_pre across a boundary).
__global__ __launch_bounds__(256) void k_front(const int* __restrict__ src,
                                               const int* __restrict__ dst,
                                               int* __restrict__ cnt,
                                               unsigned short* __restrict__ esrc_pad,
                                               const _Float16* __restrict__ WT1,
                                               const float* __restrict__ x,
                                               _Float16* __restrict__ G) {
    const int b = blockIdx.x, tid = threadIdx.x;
    if (b < SCAT_NB) {
        const int e = b * 256 + tid;
        const int s = __builtin_nontemporal_load(&src[e]);
        const int d = __builtin_nontemporal_load(&dst[e]);
        unsigned int rank = atomicAdd((unsigned int*)&cnt[d], 1u);
        if (rank < STRIDE) esrc_pad[d * STRIDE + rank] = (unsigned short)s;
        return;
    }
    // ---- gemm1 raw ----
    const int wave = tid >> 6;
    const int lane = tid & 63;
    const int task = (b - SCAT_NB) * 4 + wave;
    if (task >= G1_TASKS) return;
    const int strip = task >> 1;
    const int nh = task & 1;
    const int row0 = strip * 16;
    const int mrow = row0 + (lane & 15);
    const int kq = (lane >> 4) * 8;

    half8_t af[4];
#pragma unroll
    for (int kc = 0; kc < 4; ++kc) {
        const float* ap = x + (size_t)mrow * 128 + kc * 32 + kq;
        float4_t f0 = __builtin_nontemporal_load((const float4_t*)ap);
        float4_t f1 = __builtin_nontemporal_load((const float4_t*)(ap + 4));
        half8_t h;
        h[0] = (_Float16)f0[0]; h[1] = (_Float16)f0[1];
        h[2] = (_Float16)f0[2]; h[3] = (_Float16)f0[3];
        h[4] = (_Float16)f1[0]; h[5] = (_Float16)f1[1];
        h[6] = (_Float16)f1[2]; h[7] = (_Float16)f1[3];
        af[kc] = h;
    }
    float4_t acc[4];
#pragma unroll
    for (int nt = 0; nt < 4; ++nt) acc[nt] = (float4_t)(0.0f);
#pragma unroll
    for (int nt = 0; nt < 4; ++nt) {
        const _Float16* wp = WT1 + (size_t)((nh * 4 + nt) * 16 + (lane & 15)) * 128 + kq;
#pragma unroll
        for (int kc = 0; kc < 4; ++kc) {
            half8_t bf = *(const half8_t*)(wp + kc * 32);
            acc[nt] = __builtin_amdgcn_mfma_f32_16x16x32_f16(af[kc], bf, acc[nt], 0, 0, 0);
        }
    }
#pragma unroll
    for (int r = 0; r < 4; ++r) {
        int row = row0 + (lane >> 4) * 4 + r;
#pragma unroll
        for (int nt = 0; nt < 4; ++nt)
            G[(size_t)row * 128 + nh * 64 + nt * 16 + (lane & 15)] =
                (_Float16)acc[nt][r];
    }
}

// K_mid: one block per 16-node strip. Phase A: 4 waves aggregate 4 nodes
// each (full 128 cols; 4 edge-slots x 16 col-groups; per-edge dinv_s from
// cnt), h1 tile -> LDS (relu'd, biased). Phase B: after __syncthreads, each
// wave MFMAs the LDS tile with W2 for its 16-col output group -> g2 raw.
// h1 never touches global memory. LDS rows padded to 136 halves.
__global__ __launch_bounds__(256) void k_mid(const int* __restrict__ cnt,
                                             const unsigned short* __restrict__ esrc_pad,
                                             const _Float16* __restrict__ G,
                                             const _Float16* __restrict__ WT2,
                                             const float* __restrict__ b1,
                                             _Float16* __restrict__ g2) {
    __shared__ _Float16 h1[16][136];
    const int tid = threadIdx.x;
    const int wave = tid >> 6;
    const int lane = tid & 63;
    const int row0 = blockIdx.x * 16;
    const int eidx = lane >> 4;   // 4 edge slots
    const int fl = lane & 15;     // 16 col-groups of 8

    for (int r4 = 0; r4 < 4; ++r4) {
        const int rr = wave * 4 + r4;
        const int node = row0 + rr;
        const int end = cnt[node];
        const float dvd = rsqrtf((float)end + 1.0f);
        const int base = node * STRIDE;

        float acc[8];
#pragma unroll
        for (int p = 0; p < 8; ++p) acc[p] = 0.0f;
        if (eidx == 0) {  // self-loop term dinv_d * G[node]
            half8_t sv = *(const half8_t*)(G + (size_t)node * 128 + fl * 8);
#pragma unroll
            for (int p = 0; p < 8; ++p) acc[p] = dvd * (float)sv[p];
        }
        int j = 0;
        for (; j + 7 < end; j += 8) {
            int s0 = (int)__builtin_nontemporal_load(&esrc_pad[base + j + eidx]);
            int s1 = (int)__builtin_nontemporal_load(&esrc_pad[base + j + 4 + eidx]);
            float dv0 = rsqrtf((float)cnt[s0] + 1.0f);
            float dv1 = rsqrtf((float)cnt[s1] + 1.0f);
            half8_t r0 = *(const half8_t*)(G + (size_t)s0 * 128 + fl * 8);
            half8_t r1 = *(const half8_t*)(G + (size_t)s1 * 128 + fl * 8);
#pragma unroll
            for (int p = 0; p < 8; ++p)
                acc[p] += dv0 * (float)r0[p] + dv1 * (float)r1[p];
        }
        for (; j + 3 < end; j += 4) {
            int s = (int)__builtin_nontemporal_load(&esrc_pad[base + j + eidx]);
            float dvs = rsqrtf((float)cnt[s] + 1.0f);
            half8_t r = *(const half8_t*)(G + (size_t)s * 128 + fl * 8);
#pragma unroll
            for (int p = 0; p < 8; ++p) acc[p] += dvs * (float)r[p];
        }
        if (j < end) {
            int idx = j + eidx;
            int s = (int)__builtin_nontemporal_load(
                &esrc_pad[base + ((idx < end) ? idx : (end - 1))]);
            float valid = (idx < end) ? 1.0f : 0.0f;
            float dvs = rsqrtf((float)cnt[s] + 1.0f);
            half8_t r = *(const half8_t*)(G + (size_t)s * 128 + fl * 8);
#pragma unroll
            for (int p = 0; p < 8; ++p) acc[p] += valid * dvs * (float)r[p];
        }
        // reduce over the 4 edge slots (lane bits 4,5)
#pragma unroll
        for (int p = 0; p < 8; ++p) {
            acc[p] += __shfl_xor(acc[p], 16, 64);
            acc[p] += __shfl_xor(acc[p], 32, 64);
        }
        if (eidx == 0) {
            float4_t c0 = *(const float4_t*)(b1 + fl * 8);
            float4_t c1 = *(const float4_t*)(b1 + fl * 8 + 4);
            half8_t o;
            o[0] = (_Float16)fmaxf(acc[0] * dvd + c0[0], 0.0f);
            o[1] = (_Float16)fmaxf(acc[1] * dvd + c0[1], 0.0f);
            o[2] = (_Float16)fmaxf(acc[2] * dvd + c0[2], 0.0f);
            o[3] = (_Float16)fmaxf(acc[3] * dvd + c0[3], 0.0f);
            o[4] = (_Float16)fmaxf(acc[4] * dvd + c1[0], 0.0f);
            o[5] = (_Float16)fmaxf(acc[5] * dvd + c1[1], 0.0f);
            o[6] = (_Float16)fmaxf(acc[6] * dvd + c1[2], 0.0f);
            o[7] = (_Float16)fmaxf(acc[7] * dvd + c1[3], 0.0f);
            *(half8_t*)&h1[rr][fl * 8] = o;
        }
    }
    __syncthreads();

    // ---- Phase B: gemm2 for this strip, wave -> out cols [wave*16,+16) ----
    const int fr = lane & 15;
    const int kq = (lane >> 4) * 8;
    half8_t af[4];
#pragma unroll
    for (int kc = 0; kc < 4; ++kc)
        af[kc] = *(const half8_t*)&h1[fr][kc * 32 + kq];
    float4_t acc2 = (float4_t)(0.0f);
    const _Float16* wp = WT2 + (size_t)(wave * 16 + fr) * 128 + kq;
#pragma unroll
    for (int kc = 0; kc < 4; ++kc) {
        half8_t bf = *(const half8_t*)(wp + kc * 32);
        acc2 = __builtin_amdgcn_mfma_f32_16x16x32_f16(af[kc], bf, acc2, 0, 0, 0);
    }
#pragma unroll
    for (int r = 0; r < 4; ++r) {
        int row = row0 + (lane >> 4) * 4 + r;
        g2[(size_t)row * 64 + wave * 16 + fr] = (_Float16)acc2[r];
    }
}

// K_back: agg64 with per-edge dinv. One wave/node, 16 edges/iter.
// out_d = dvd*(sum_e dvs*g2_s + dvd*g2_d) + b2, fp32 NT stores.
__global__ __launch_bounds__(256) void k_back(const int* __restrict__ cnt,
                                              const unsigned short* __restrict__ esrc_pad,
                                              const _Float16* __restrict__ g2,
                                              const float* __restrict__ b2,
                                              float* __restrict__ out) {
    const int wave = threadIdx.x >> 6;
    const int lane = threadIdx.x & 63;
    const int node = blockIdx.x * 4 + wave;
    if (node >= N_NODES) return;
    const int eidx = lane >> 3;
    const int fl = lane & 7;

    const int end = cnt[node];
    const float dvd = rsqrtf((float)end + 1.0f);
    const int base = node * STRIDE;

    float acc[8];
#pragma unroll
    for (int p = 0; p < 8; ++p) acc[p] = 0.0f;
    if (lane < 8) {  // self term
        half8_t s = *(const half8_t*)(g2 + (size_t)node * 64 + fl * 8);
#pragma unroll
        for (int p = 0; p < 8; ++p) acc[p] = dvd * (float)s[p];
    }

    int j = 0;
    for (; j + 15 < end; j += 16) {
        int s0 = (int)__builtin_nontemporal_load(&esrc_pad[base + j + eidx]);
        int s1 = (int)__builtin_nontemporal_load(&esrc_pad[base + j + 8 + eidx]);
        float dv0 = rsqrtf((float)cnt[s0] + 1.0f);
        float dv1 = rsqrtf((float)cnt[s1] + 1.0f);
        half8_t r0 = *(const half8_t*)(g2 + (size_t)s0 * 64 + fl * 8);
        half8_t r1 = *(const half8_t*)(g2 + (size_t)s1 * 64 + fl * 8);
#pragma unroll
        for (int p = 0; p < 8; ++p)
            acc[p] += dv0 * (float)r0[p] + dv1 * (float)r1[p];
    }
    for (; j + 7 < end; j += 8) {
        int s = (int)__builtin_nontemporal_load(&esrc_pad[base + j + eidx]);
        float dvs = rsqrtf((float)cnt[s] + 1.0f);
        half8_t r = *(const half8_t*)(g2 + (size_t)s * 64 + fl * 8);
#pragma unroll
        for (int p = 0; p < 8; ++p) acc[p] += dvs * (float)r[p];
    }
    if (j < end) {
        int idx = j + eidx;
        int s = (int)__builtin_nontemporal_load(
            &esrc_pad[base + ((idx < end) ? idx : (end - 1))]);
        float valid = (idx < end) ? 1.0f : 0.0f;
        float dvs = rsqrtf((float)cnt[s] + 1.0f);
        half8_t r = *(const half8_t*)(g2 + (size_t)s * 64 + fl * 8);
#pragma unroll
        for (int p = 0; p < 8; ++p) acc[p] += valid * dvs * (float)r[p];
    }

#pragma unroll
    for (int p = 0; p < 8; ++p) {
        acc[p] += __shfl_xor(acc[p], 32, 64);
        acc[p] += __shfl_xor(acc[p], 16, 64);
        acc[p] += __shfl_xor(acc[p], 8, 64);
    }

    if (lane < 8) {
        float4_t c0 = *(const float4_t*)(b2 + fl * 8);
        float4_t c1 = *(const float4_t*)(b2 + fl * 8 + 4);
        float4_t o0, o1;
        o0[0] = acc[0] * dvd + c0[0]; o0[1] = acc[1] * dvd + c0[1];
        o0[2] = acc[2] * dvd + c0[2]; o0[3] = acc[3] * dvd + c0[3];
        o1[0] = acc[4] * dvd + c1[0]; o1[1] = acc[5] * dvd + c1[1];
        o1[2] = acc[6] * dvd + c1[2]; o1[3] = acc[7] * dvd + c1[3];
        __builtin_nontemporal_store(o0, (float4_t*)(out + (size_t)node * 64 + fl * 8));
        __builtin_nontemporal_store(o1, (float4_t*)(out + (size_t)node * 64 + fl * 8 + 4));
    }
}

extern "C" void kernel_launch(void* const* d_in, const int* in_sizes, int n_in,
                              void* d_out, int out_size, void* d_ws, size_t ws_size,
                              hipStream_t stream) {
    const float* x  = (const float*)d_in[0];
    const int*   ei = (const int*)d_in[1];
    const float* W1 = (const float*)d_in[2];
    const float* b1 = (const float*)d_in[3];
    const float* W2 = (const float*)d_in[4];
    const float* b2 = (const float*)d_in[5];

    const int* src = ei;
    const int* dst = ei + N_EDGES;

    char* w = (char*)d_ws;
    unsigned short* esrc_pad = (unsigned short*)w; w += sizeof(unsigned short) * (size_t)N_NODES * STRIDE;
    _Float16*       G        = (_Float16*)w;       w += sizeof(_Float16) * (size_t)N_NODES * 128;
    _Float16*       g2       = (_Float16*)w;       w += sizeof(_Float16) * (size_t)N_NODES * OUT_DIM;
    _Float16*       WT1      = (_Float16*)w;       w += sizeof(_Float16) * 128 * 128;
    _Float16*       WT2      = (_Float16*)w;       w += sizeof(_Float16) * 64 * 128;
    int*            cnt      = (int*)w;            w += sizeof(int) * N_NODES;
    float*          out      = (float*)d_out;

    k_pre<<<PRE_NB, 256, 0, stream>>>(W1, W2, WT1, WT2, cnt);
    k_front<<<SCAT_NB + G1_NB, 256, 0, stream>>>(src, dst, cnt, esrc_pad, WT1, x, G);
    k_mid<<<N_NODES / 16, 256, 0, stream>>>(cnt, esrc_pad, G, WT2, b1, g2);
    k_back<<<(N_NODES + 3) / 4, 256, 0, stream>>>(cnt, esrc_pad, g2, b2, out);
}